// Round 7
// baseline (94.736 us; speedup 1.0000x reference)
//
#include <hip/hip_runtime.h>
#include <math.h>

#define NT_ 365
#define NS_ 1024
#define NH_ 64
#define NG_ 32
#define NW_ 514        // NH*8 + 2
#define PH_ 32         // timesteps per phase
#define NPH_ 12        // 12*32 = 384 >= 365; tail steps are harmless dummies
#define CH_ 64         // timesteps per output chunk (= 2 phases)
#define YPAD_ 65       // padded ytile row stride: conflict-free R/W

__device__ __forceinline__ float sigmoidf(float v) {
  return 1.0f / (1.0f + expf(-v));
}

// met = (Ps, Pl, relu(Ta), E); relu folded since gm > 0
__device__ __forceinline__ float4 compute_met(float4 xv) {
  const float P = xv.x, E = xv.y, T1 = xv.z, T2 = xv.w;
  const float Ta = (T1 + T2) * 0.5f;
  float rP;
  if (T2 <= 0.0f) {
    rP = 0.0f;
  } else if (T1 >= 0.0f) {
    rP = 1.0f;
  } else {
    float r = (T1 + T2) / (T2 - T1);
    r = fminf(fmaxf(r, -0.999999f), 0.999999f);
    rP = 1.0f - acosf(r) * (1.0f / 3.1415f);
  }
  float4 m;
  m.x = (1.0f - rP) * P;
  m.y = rP * P;
  m.z = fmaxf(Ta, 0.0f);
  m.w = E;
  return m;
}

// CROSS-SIMD PIPELINE SPLIT. Model from R3/R5: wave issue cadence ~8 cyc/inst
// solo, ~4 with two interleaved streams, floor 2 -> within-wave packing is
// wall-invariant (measured); the only lever is a SHORTER stream per SIMD.
// Per site: wave A runs the serial S+H chains (~12 insts/site-step), exports
// z; wave B (different SIMD) recomputes Hh/M from z, runs the G/y chain,
// the y-reduce, and precomputes met -> phases of 32 steps, B one phase
// behind, double-buffered z/met, 13 barriers total. Both waves carry 2
// sites so independent streams fill dep-stall gaps (R5's proven 4-cyc
// cadence). Feeds avoid stalls: A's met = uniform-address LDS reads,
// group-double-buffered; B's z = lane-strided reads a full phase behind.
__global__ __launch_bounds__(256) void waternet_scan(
    const float* __restrict__ x,     // [NT, NS, 4]
    const float* __restrict__ xc,    // [NS, NG]
    const float* __restrict__ fc_w,  // [NW, NG]
    const float* __restrict__ fc_b,  // [NW]
    float* __restrict__ out)         // [NT, NS]
{
  __shared__ float  zbuf[2][4][PH_][NH_];   // 64 KB: dbuf x slot x step x h
  __shared__ float4 metb[2][4][PH_];        // 4 KB:  dbuf x slot x step
  __shared__ float  ytile[4][CH_ * YPAD_];  // 66.6 KB: per-slot y rows

  const int tid  = threadIdx.x;
  const int lane = tid & 63;
  const int wv   = tid >> 6;
  const bool isA = (wv < 2);          // waves 0,1 = chain (A); 2,3 = tail (B)
  const int s0   = (wv & 1) * 2;      // this wave's two site slots
  const int s1   = s0 + 1;
  const int base = blockIdx.x << 2;
  const int site0 = base + s0, site1 = base + s1;
  const float4* xp  = (const float4*)x;
  const float4* wq4 = (const float4*)fc_w;
  const int us0 = __builtin_amdgcn_readfirstlane(site0);
  const float4* xcq0 = (const float4*)(xc + us0 * NG_);
  const float4* xcq1 = (const float4*)(xc + (us0 + 1) * NG_);

  // A-role state (2 sites)
  float gm0=0,nge0=0,gi0=0,mgo0=0,glA0=0,S0a=0,H0a=0;
  float gm1=0,nge1=0,gi1=0,mgo1=0,glA1=0,S0b=0,H0b=0;
  // B-role state (2 sites); Gh = (ga*kb)*G so y = Gh + fmaf(c1,M, ga*Hh)
  float glB0=0,kb1m0=0,cgb0=0,c10=0,ga0=0,qb0=0,Gh0=0;
  float glB1=0,kb1m1=0,cgb1=0,c11=0,ga1=0,qb1=0,Gh1=0;

  // B met mapping: lanes 0-31 -> slot s0, lanes 32-63 -> slot s1
  const int mslot = s0 + (lane >> 5);
  const int msite = base + mslot;
  const int mt    = lane & 31;

  if (isA) {
    // ---- A prologue: GEMM rows {gm, ge, go, gl, gi} x 2 sites, shared w
    float a0[5], a1[5];
    const int rows[5] = {0, 1, 2, 3, 7};
#pragma unroll
    for (int k = 0; k < 5; ++k) { a0[k] = fc_b[rows[k]*NH_ + lane]; a1[k] = a0[k]; }
#pragma unroll
    for (int g4 = 0; g4 < NG_/4; ++g4) {
      const float4 x0 = xcq0[g4];
      const float4 x1 = xcq1[g4];
#pragma unroll
      for (int k = 0; k < 5; ++k) {
        const float4 w = wq4[(rows[k]*NH_ + lane)*(NG_/4) + g4];
        a0[k]=fmaf(x0.x,w.x,a0[k]); a0[k]=fmaf(x0.y,w.y,a0[k]);
        a0[k]=fmaf(x0.z,w.z,a0[k]); a0[k]=fmaf(x0.w,w.w,a0[k]);
        a1[k]=fmaf(x1.x,w.x,a1[k]); a1[k]=fmaf(x1.y,w.y,a1[k]);
        a1[k]=fmaf(x1.z,w.z,a1[k]); a1[k]=fmaf(x1.w,w.w,a1[k]);
      }
    }
    gm0=expf(a0[0])+1.f; nge0=-2.f*sigmoidf(a0[1]); mgo0=-sigmoidf(a0[2]);
    glA0=expf(a0[3]*2.f); gi0=sigmoidf(a0[4]);
    gm1=expf(a1[0])+1.f; nge1=-2.f*sigmoidf(a1[1]); mgo1=-sigmoidf(a1[2]);
    glA1=expf(a1[3]*2.f); gi1=sigmoidf(a1[4]);
    __builtin_amdgcn_s_setprio(1);     // critical chain wave
  } else {
    // ---- B prologue: phase-0 x first (latency under GEMM), 5+q rows x 2
    float4 xv0m = xp[mt * NS_ + msite];
    float a0[5], a1[5];
    const int rows[5] = {2, 3, 4, 5, 6};
#pragma unroll
    for (int k = 0; k < 5; ++k) { a0[k] = fc_b[rows[k]*NH_ + lane]; a1[k] = a0[k]; }
    float aq0 = fc_b[NW_-1], aq1 = aq0;
#pragma unroll
    for (int g4 = 0; g4 < NG_/4; ++g4) {
      const float4 x0 = xcq0[g4];
      const float4 x1 = xcq1[g4];
#pragma unroll
      for (int k = 0; k < 5; ++k) {
        const float4 w = wq4[(rows[k]*NH_ + lane)*(NG_/4) + g4];
        a0[k]=fmaf(x0.x,w.x,a0[k]); a0[k]=fmaf(x0.y,w.y,a0[k]);
        a0[k]=fmaf(x0.z,w.z,a0[k]); a0[k]=fmaf(x0.w,w.w,a0[k]);
        a1[k]=fmaf(x1.x,w.x,a1[k]); a1[k]=fmaf(x1.y,w.y,a1[k]);
        a1[k]=fmaf(x1.z,w.z,a1[k]); a1[k]=fmaf(x1.w,w.w,a1[k]);
      }
      {
        const float4 w = wq4[(NW_-1)*(NG_/4) + g4];
        aq0=fmaf(x0.x,w.x,aq0); aq0=fmaf(x0.y,w.y,aq0);
        aq0=fmaf(x0.z,w.z,aq0); aq0=fmaf(x0.w,w.w,aq0);
        aq1=fmaf(x1.x,w.x,aq1); aq1=fmaf(x1.y,w.y,aq1);
        aq1=fmaf(x1.z,w.z,aq1); aq1=fmaf(x1.w,w.w,aq1);
      }
    }
    {
      const float go = sigmoidf(a0[0]);
      glB0 = expf(a0[1]*2.f);
      float mx = a0[2];
#pragma unroll
      for (int m2=32;m2>=1;m2>>=1) mx = fmaxf(mx, __shfl_xor(mx,m2,64));
      const float ex = expf(a0[2]-mx);
      float sm = ex;
#pragma unroll
      for (int m2=32;m2>=1;m2>>=1) sm += __shfl_xor(sm,m2,64);
      ga0 = ex/sm;
      const float gb = sigmoidf(a0[3]);
      const float kb = 0.1f*sigmoidf(a0[4]);
      qb0 = fmaxf(aq0,0.f)*(1.f/NH_);
      kb1m0 = 1.f-kb; cgb0 = ga0*kb*gb*go; c10 = ga0*(go*(1.f-gb)-1.f);
    }
    {
      const float go = sigmoidf(a1[0]);
      glB1 = expf(a1[1]*2.f);
      float mx = a1[2];
#pragma unroll
      for (int m2=32;m2>=1;m2>>=1) mx = fmaxf(mx, __shfl_xor(mx,m2,64));
      const float ex = expf(a1[2]-mx);
      float sm = ex;
#pragma unroll
      for (int m2=32;m2>=1;m2>>=1) sm += __shfl_xor(sm,m2,64);
      ga1 = ex/sm;
      const float gb = sigmoidf(a1[3]);
      const float kb = 0.1f*sigmoidf(a1[4]);
      qb1 = fmaxf(aq1,0.f)*(1.f/NH_);
      kb1m1 = 1.f-kb; cgb1 = ga1*kb*gb*go; c11 = ga1*(go*(1.f-gb)-1.f);
    }
    metb[0][mslot][mt] = compute_met(xv0m);   // phase-0 met
  }

  // ---- A: produce one 32-step phase of z (2 sites, group-dbuf met feed)
  auto produceA = [&](int p) {
    const int pb = p & 1;
    float4 ma[8], mb[8], na[8], nb[8];
#pragma unroll
    for (int i=0;i<8;++i){ ma[i]=metb[pb][s0][i]; mb[i]=metb[pb][s1][i]; }
#pragma unroll
    for (int g=0; g<4; ++g) {
      float4* cA=(g&1)?na:ma; float4* cB=(g&1)?nb:mb;
      float4* nA=(g&1)?ma:na; float4* nB=(g&1)?mb:nb;
      if (g<3) {
#pragma unroll
        for (int i=0;i<8;++i){
          nA[i]=metb[pb][s0][(g+1)*8+i];
          nB[i]=metb[pb][s1][(g+1)*8+i];
        }
      }
#pragma unroll
      for (int u=0; u<8; ++u) {
        const int uu = g*8+u;
        {
          const float4 m = cA[u];
          const float melt = m.z*gm0;
          const float Sm   = fminf(S0a, melt);
          const float tS   = S0a + m.x;
          S0a = tS - Sm;
          const float d = fmaf(m.y, gi0, fmaf(m.w, nge0, Sm));
          const float z = H0a + d;
          zbuf[pb][s0][uu][lane] = z;
          const float Hh = fmaxf(z, 0.f);
          const float M  = __builtin_amdgcn_fmed3f(z, 0.f, glA0);
          H0a = fminf(fmaf(mgo0, M, Hh), glA0);
        }
        {
          const float4 m = cB[u];
          const float melt = m.z*gm1;
          const float Sm   = fminf(S0b, melt);
          const float tS   = S0b + m.x;
          S0b = tS - Sm;
          const float d = fmaf(m.y, gi1, fmaf(m.w, nge1, Sm));
          const float z = H0b + d;
          zbuf[pb][s1][uu][lane] = z;
          const float Hh = fmaxf(z, 0.f);
          const float M  = __builtin_amdgcn_fmed3f(z, 0.f, glA1);
          H0b = fminf(fmaf(mgo1, M, Hh), glA1);
        }
      }
    }
  };

  // ---- B: consume one phase of z -> G/y chain -> ytile (2 sites)
  auto consumeB = [&](int q) {
    const int qb2 = q & 1;
    const int tb  = qb2 * PH_;        // chunk-local row base
    float za[8], zb[8], wa[8], wb[8];
#pragma unroll
    for (int i=0;i<8;++i){ za[i]=zbuf[qb2][s0][i][lane]; zb[i]=zbuf[qb2][s1][i][lane]; }
#pragma unroll
    for (int g=0; g<4; ++g) {
      float* cA=(g&1)?wa:za; float* cB=(g&1)?wb:zb;
      float* nA=(g&1)?za:wa; float* nB=(g&1)?zb:wb;
      if (g<3) {
#pragma unroll
        for (int i=0;i<8;++i){
          nA[i]=zbuf[qb2][s0][(g+1)*8+i][lane];
          nB[i]=zbuf[qb2][s1][(g+1)*8+i][lane];
        }
      }
#pragma unroll
      for (int u=0; u<8; ++u) {
        const int tl = tb + g*8 + u;
        {
          const float z  = cA[u];
          const float Hh = fmaxf(z, 0.f);
          const float M  = __builtin_amdgcn_fmed3f(z, 0.f, glB0);
          Gh0 = fmaf(kb1m0, Gh0, cgb0*M);
          ytile[s0][tl*YPAD_ + lane] = Gh0 + fmaf(c10, M, ga0*Hh);
        }
        {
          const float z  = cB[u];
          const float Hh = fmaxf(z, 0.f);
          const float M  = __builtin_amdgcn_fmed3f(z, 0.f, glB1);
          Gh1 = fmaf(kb1m1, Gh1, cgb1*M);
          ytile[s1][tl*YPAD_ + lane] = Gh1 + fmaf(c11, M, ga1*Hh);
        }
      }
    }
  };

  // ---- B: transposed per-chunk reduce + store (bank=(t'+h)%32, free)
  auto reduceB = [&](int c) {
    const float* y0 = &ytile[s0][lane*YPAD_];
    const float* y1 = &ytile[s1][lane*YPAD_];
    float r0=0,r1=0,r2=0,r3=0, t0=0,t1=0,t2=0,t3=0;
#pragma unroll
    for (int h=0; h<CH_; h+=4) {
      r0+=y0[h]; r1+=y0[h+1]; r2+=y0[h+2]; r3+=y0[h+3];
      t0+=y1[h]; t1+=y1[h+1]; t2+=y1[h+2]; t3+=y1[h+3];
    }
    const int t_out = c*CH_ + lane;
    if (t_out < NT_) {
      out[t_out*NS_ + site0] = ((r0+r1)+(r2+r3)) + qb0;
      out[t_out*NS_ + site1] = ((t0+t1)+(t2+t3)) + qb1;
    }
  };

  __syncthreads();   // phase-0 met visible to A

#pragma unroll 1
  for (int p = 0; p < NPH_; ++p) {
    if (isA) {
      produceA(p);                         // z for phase p -> zbuf[p&1]
    } else {
      float4 xvm = make_float4(0.f,0.f,0.f,0.f);
      const bool hm = (p + 1 < NPH_);
      if (hm) {                            // x for phase p+1 met, issued early
        int tg = PH_*(p+1) + mt;
        if (tg > NT_-1) tg = NT_-1;
        xvm = xp[tg*NS_ + msite];
      }
      if (p > 0) {
        consumeB(p-1);                     // phase p-1 from zbuf[(p-1)&1]
        if ((p-1) & 1) reduceB((p-1) >> 1);
      }
      if (hm) metb[(p+1)&1][mslot][mt] = compute_met(xvm);
    }
    __syncthreads();
  }
  if (!isA) { consumeB(NPH_-1); reduceB((NPH_-1) >> 1); }   // drain phase 11
}

extern "C" void kernel_launch(void* const* d_in, const int* in_sizes, int n_in,
                              void* d_out, int out_size, void* d_ws, size_t ws_size,
                              hipStream_t stream) {
  const float* x    = (const float*)d_in[0];
  const float* xc   = (const float*)d_in[1];
  const float* fc_w = (const float*)d_in[2];
  const float* fc_b = (const float*)d_in[3];
  float* out = (float*)d_out;

  // 4 sites/block, each split across an A-wave pair-slot and a B-wave
  // pair-slot -> 256 threads, 256 blocks, 136 KB LDS -> 1 block/CU,
  // 4 waves/CU = 1 wave/SIMD: A and B streams run on SEPARATE SIMDs,
  // halving the in-order instruction stream each SIMD must pace through.
  hipLaunchKernelGGL(waternet_scan, dim3(NS_ / 4), dim3(256), 0, stream,
                     x, xc, fc_w, fc_b, out);
}

// Round 8
// 90.325 us; speedup vs baseline: 1.0488x; 1.0488x over previous
//
#include <hip/hip_runtime.h>
#include <math.h>

#define NT_ 365
#define NS_ 1024
#define NH_ 64
#define NG_ 32
#define NW_ 514        // NH*8 + 2
#define CH_ 64         // timesteps per chunk (= wave size)
#define NCHUNK_ 6      // ceil(365/64); tail steps are harmless dummies
#define YPAD_ 65       // padded ytile row stride: conflict-free R/W

__device__ __forceinline__ float sigmoidf(float v) {
  return 1.0f / (1.0f + expf(-v));
}

// broadcast lane l's float to all lanes (compile-time l in unrolled loops)
__device__ __forceinline__ float rdl(float v, int l) {
  return __int_as_float(__builtin_amdgcn_readlane(__float_as_int(v), l));
}

// met = (Ps, Pl, relu(Ta), E); relu folded since gm > 0
__device__ __forceinline__ float4 compute_met(float4 xv) {
  const float P = xv.x, E = xv.y, T1 = xv.z, T2 = xv.w;
  const float Ta = (T1 + T2) * 0.5f;
  float rP;
  if (T2 <= 0.0f) {
    rP = 0.0f;
  } else if (T1 >= 0.0f) {
    rP = 1.0f;
  } else {
    float r = (T1 + T2) / (T2 - T1);
    r = fminf(fmaxf(r, -0.999999f), 0.999999f);
    rP = 1.0f - acosf(r) * (1.0f / 3.1415f);
  }
  float4 m;
  m.x = (1.0f - rP) * P;
  m.y = rP * P;
  m.z = fmaxf(Ta, 0.0f);
  m.w = E;
  return m;
}

// SPLIT-CHAIN PIPELINE (R6 + 1-step-ahead d). Measured model: a wave's issue
// cadence is ~7.5 cyc/inst with ONE dependence stream and ~4.1 with TWO
// interleaved streams (R5: 2 sites, 38 insts, same 160 cyc/step as R6's 22).
// So instead of a 2nd site, split THIS site's 8-deep fused chain into two
// short independent chains by producing d_{t+1} (snow chain, depth 3) while
// consuming d_t (H/G/y chain, depth 4). Same 22 insts/step as R6, but now
// they form two streams that fill each other's dep gaps -> predicted
// ~90 cyc/step. Readlane met feed (R6-proven), dA/dB static rotation
// (no runtime indexing -> no scratch), no barriers, no LDS but ytile.
__global__ __launch_bounds__(256) void waternet_scan(
    const float* __restrict__ x,     // [NT, NS, 4]
    const float* __restrict__ xc,    // [NS, NG]
    const float* __restrict__ fc_w,  // [NW, NG]
    const float* __restrict__ fc_b,  // [NW]
    float* __restrict__ out)         // [NT, NS]
{
  __shared__ float ytile[4][CH_ * YPAD_];  // 66.6 KB: per-wave y rows

  const int tid  = threadIdx.x;
  const int lane = tid & 63;
  const int wv   = tid >> 6;
  const int site = (blockIdx.x << 2) + wv;
  const int us   = __builtin_amdgcn_readfirstlane(site);
  const float4* xp = (const float4*)x;

  // chunk-0 prefetch first: HBM latency hides under the gate GEMM
  float4 xcur = xp[lane * NS_ + site];  // t = lane

  // ---- prologue GEMM: w[site, j] = xc[site,:] . fc_w[j,:] + fc_b[j]
  float acc[8];
#pragma unroll
  for (int k = 0; k < 8; ++k) acc[k] = fc_b[k * NH_ + lane];
  float accq = fc_b[NW_ - 1];

  const float4* xcq = (const float4*)(xc + us * NG_);
  const float4* wq4 = (const float4*)fc_w;
#pragma unroll
  for (int g4 = 0; g4 < NG_ / 4; ++g4) {
    const float4 xv = xcq[g4];
#pragma unroll
    for (int k = 0; k < 8; ++k) {
      const float4 w = wq4[(k * NH_ + lane) * (NG_ / 4) + g4];
      acc[k] = fmaf(xv.x, w.x, acc[k]);
      acc[k] = fmaf(xv.y, w.y, acc[k]);
      acc[k] = fmaf(xv.z, w.z, acc[k]);
      acc[k] = fmaf(xv.w, w.w, acc[k]);
    }
    {
      const float4 w = wq4[(NW_ - 1) * (NG_ / 4) + g4];
      accq = fmaf(xv.x, w.x, accq);
      accq = fmaf(xv.y, w.y, accq);
      accq = fmaf(xv.z, w.z, accq);
      accq = fmaf(xv.w, w.w, accq);
    }
  }

  // ---- gates (per-lane = per hidden unit), folded constants
  const float gm  = expf(acc[0]) + 1.0f;
  const float ngm = -gm;                         // a = fmaf(Tz, ngm, Ps)
  const float nge = -2.0f * sigmoidf(acc[1]);    // -ge
  const float go  = sigmoidf(acc[2]);
  const float gl  = expf(acc[3] * 2.0f);
  float mx = acc[4];
#pragma unroll
  for (int m2 = 32; m2 >= 1; m2 >>= 1) mx = fmaxf(mx, __shfl_xor(mx, m2, 64));
  const float ex = expf(acc[4] - mx);
  float sm = ex;
#pragma unroll
  for (int m2 = 32; m2 >= 1; m2 >>= 1) sm += __shfl_xor(sm, m2, 64);
  const float ga = ex / sm;
  const float gb = sigmoidf(acc[5]);
  const float kb = sigmoidf(acc[6]) * 0.1f;
  const float gi = sigmoidf(acc[7]);
  const float qb = fmaxf(accq, 0.0f) * (1.0f / NH_);
  const float mgo  = -go;
  const float kb1m = 1.0f - kb;
  const float cgm  = ga * kb * gb * go;              // Gy feed coeff
  const float c1   = ga * (go * (1.0f - gb) - 1.0f); // y = ga*Hh + c1*M + Gy

  // ---- scan state; Gy = ga*kb*G (exact rescale of the G recurrence)
  float S0 = 0.0f, H0 = 0.0f, Gy = 0.0f;
  float dA, dB;   // 1-step-ahead d pipeline, static rotation (no indexing)

  // met for the CURRENT chunk lives across lanes: lane = local timestep
  float4 mm = compute_met(xcur);

  // snow stream (chain: a -> add -> max, depth 3): met(i), S_{i-1} -> d_i, S_i
  // Sn = max(S0+a, Ps) == S0 - min(S0,melt) + Ps; Sm = (S0-Sn)+Ps = min(S0,melt)
  auto stg = [&](int i, float& dout) {
    const float Ps = rdl(mm.x, i);
    const float Pl = rdl(mm.y, i);
    const float Tz = rdl(mm.z, i);
    const float Ev = rdl(mm.w, i);
    const float a  = fmaf(Tz, ngm, Ps);
    const float Sn = fmaxf(S0 + a, Ps);
    const float Sm = (S0 - Sn) + Ps;
    dout = fmaf(Pl, gi, fmaf(Ev, nge, Sm));
    S0 = Sn;
  };

  // H/G/y stream (chain: z -> fmed3 -> fmaf -> min, depth 4)
  auto cns = [&](float d, float* yp) {
    const float z  = H0 + d;
    const float Hh = fmaxf(z, 0.0f);
    const float M  = __builtin_amdgcn_fmed3f(z, 0.0f, gl);  // min(H, gl)
    H0 = fminf(fmaf(mgo, M, Hh), gl);
    Gy = fmaf(kb1m, Gy, cgm * M);
    *yp = Gy + fmaf(c1, M, ga * Hh);
  };

  float*       yw = &ytile[wv][lane];          // step j writes yw[j*YPAD_]
  const float* yr = &ytile[wv][lane * YPAD_];  // reduce: lane sums its row

  // pipeline fill: d for global step 0
  stg(0, dA);

#pragma unroll 1   // keep body I-cache resident across 6 iterations
  for (int c = 0; c < NCHUNK_; ++c) {
    // prefetch chunk c+1 from HBM (clamped dummy tail) — in flight all chunk
    int tn = (c + 1) * CH_ + lane;
    tn = (tn < NT_) ? tn : (NT_ - 1);
    const float4 xnext = xp[tn * NS_ + site];

    // ---- 64 steps: consume d_t (H-stream) while producing d_{t+1}
    // (S-stream). Two short chains interleave -> R5's 4-cyc cadence.
#pragma unroll
    for (int j2 = 0; j2 < 31; ++j2) {
      const int u = 2 * j2;
      cns(dA, yw + u * YPAD_);
      stg(u + 1, dB);
      cns(dB, yw + (u + 1) * YPAD_);
      stg(u + 2, dA);
    }
    cns(dA, yw + 62 * YPAD_);   // tail pair: steps 62, 63; stage 64 deferred
    stg(63, dB);
    cns(dB, yw + 63 * YPAD_);

    // ---- transposed reduction: lane t' sums row t' (bank=(t'+h)%32, free);
    // same-wave DS ordering makes the writes above visible without a barrier
    float r0 = 0.0f, r1 = 0.0f, r2 = 0.0f, r3 = 0.0f;
#pragma unroll
    for (int h = 0; h < CH_; h += 4) {
      r0 += yr[h + 0];
      r1 += yr[h + 1];
      r2 += yr[h + 2];
      r3 += yr[h + 3];
    }
    const int t_out = c * CH_ + lane;
    if (t_out < NT_) out[t_out * NS_ + site] = ((r0 + r1) + (r2 + r3)) + qb;

    // chunk top for c+1: new met into lane-regs, then the deferred stage(0)
    if (c + 1 < NCHUNK_) {
      mm = compute_met(xnext);
      stg(0, dA);
    }
  }
}

extern "C" void kernel_launch(void* const* d_in, const int* in_sizes, int n_in,
                              void* d_out, int out_size, void* d_ws, size_t ws_size,
                              hipStream_t stream) {
  const float* x    = (const float*)d_in[0];
  const float* xc   = (const float*)d_in[1];
  const float* fc_w = (const float*)d_in[2];
  const float* fc_b = (const float*)d_in[3];
  float* out = (float*)d_out;

  // 1024 sites, one wave each; 4 waves/block -> 256 blocks, ~1 wave/SIMD.
  hipLaunchKernelGGL(waternet_scan, dim3(NS_ / 4), dim3(256), 0, stream,
                     x, xc, fc_w, fc_b, out);
}